// Round 8
// baseline (668.014 us; speedup 1.0000x reference)
//
#include <hip/hip_runtime.h>
#include <cstdint>
#include <cstddef>

#define N_NODES 100000
#define D_IN 512
#define ALPHA 0.1f
#define EPS_BN 1e-5f
#define M_TILE 128
#define BK 64

// ---- CSR build: 256-node bins, tile-staged counting sort ----
#define CBITS 8
#define CNODES 256
#define NCBIN 391            // ceil(100000/256)
#define TILE 8192
#define EPT 32               // edges per thread (256 threads * 32 = 8192)
#define BINCAP 9216          // per-bin fixed capacity (mean 8192 + 11 sigma)

// ---- propagation: edge-parallel segmented reduction ----
#define NPB 64               // nodes per block
#define NB2 1563             // ceil(100000/64)
#define LCAP3 3072           // index slice capacity (mean 2048 + ~22 sigma)
#define PMAX 12              // max edges/thread = ceil(LCAP3/256)

typedef float f32x4 __attribute__((ext_vector_type(4)));
typedef __bf16 bf16x8 __attribute__((ext_vector_type(8)));
typedef unsigned short u16x8 __attribute__((ext_vector_type(8)));
typedef unsigned short u16x4 __attribute__((ext_vector_type(4)));

__device__ __forceinline__ unsigned short f2bf(float f) {
  unsigned u = __float_as_uint(f);
  u += 0x7fffu + ((u >> 16) & 1u);   // RNE
  return (unsigned short)(u >> 16);
}
__device__ __forceinline__ float bf2f(unsigned short h) {
  return __uint_as_float(((unsigned)h) << 16);
}

// ---------------- prep: fold BN into weights (bf16) + biases, zero bin cursors ----------------
__global__ void k_prep(const float* __restrict__ w1, const float* __restrict__ b1,
                       const float* __restrict__ g1, const float* __restrict__ be1,
                       const float* __restrict__ m1, const float* __restrict__ v1,
                       const float* __restrict__ w2, const float* __restrict__ b2,
                       const float* __restrict__ g2, const float* __restrict__ be2,
                       const float* __restrict__ m2, const float* __restrict__ v2,
                       unsigned short* __restrict__ w1b, unsigned short* __restrict__ w2b,
                       float* __restrict__ bias1, float* __restrict__ bias2,
                       int* __restrict__ bincur) {
  int idx = blockIdx.x * 256 + threadIdx.x;
  if (idx < 65536) {                       // w1: [128][512], scale row n by s1[n]
    int n = idx >> 9;
    float s = g1[n] * rsqrtf(v1[n] + EPS_BN);
    w1b[idx] = f2bf(w1[idx] * s);
  } else if (idx < 81920) {                // w2: [128][128]
    int i = idx - 65536;
    int n = i >> 7;
    float s = g2[n] * rsqrtf(v2[n] + EPS_BN);
    w2b[i] = f2bf(w2[i] * s);
  } else if (idx < 82048) {
    int c = idx - 81920;
    float s = g1[c] * rsqrtf(v1[c] + EPS_BN);
    bias1[c] = (b1[c] - m1[c]) * s + be1[c];
  } else if (idx < 82176) {
    int c = idx - 82048;
    float s = g2[c] * rsqrtf(v2[c] + EPS_BN);
    bias2[c] = (b2[c] - m2[c]) * s + be2[c];
  }
  int bi = idx - 82176;
  if (bi >= 0 && bi < NCBIN) bincur[bi] = 0;
}

// ---------------- scan of per-bin edge counts (bsum[b] == bincur[b]) ----------------
#define NB_SCAN 391
__global__ void k_scan2(const int* __restrict__ bincur, int* __restrict__ bsum) {
  __shared__ int s[448];
  int t = threadIdx.x;
  for (int i = t; i < 448; i += 256) s[i] = (i < NB_SCAN) ? bincur[i] : 0;
  __syncthreads();
  if (t < 64) {
    int base = t * 7;
    int vals[7];
    int sum = 0;
#pragma unroll
    for (int j = 0; j < 7; ++j) { vals[j] = s[base + j]; sum += vals[j]; }
    int x = sum;
#pragma unroll
    for (int off = 1; off < 64; off <<= 1) {
      int y = __shfl_up(x, off, 64);
      if (t >= off) x += y;
    }
    int run = x - sum;   // exclusive prefix of lane sums
#pragma unroll
    for (int j = 0; j < 7; ++j) { int tmp = vals[j]; s[base + j] = run; run += tmp; }
  }
  __syncthreads();
  for (int i = t; i < NB_SCAN; i += 256) bsum[i] = s[i];
}

__global__ void k_scan3(const int* __restrict__ deg, const int* __restrict__ bsum,
                        int* __restrict__ row_start, float* __restrict__ dinv, int E) {
  __shared__ int sb[2][256];
  int t = threadIdx.x;
  int i = blockIdx.x * 256 + t;
  int d = (i < N_NODES) ? deg[i] : 0;
  sb[0][t] = d;
  __syncthreads();
  int cur = 0;
#pragma unroll
  for (int off = 1; off < 256; off <<= 1) {
    int val = sb[cur][t] + ((t >= off) ? sb[cur][t - off] : 0);
    sb[cur ^ 1][t] = val;
    __syncthreads();
    cur ^= 1;
  }
  int incl = sb[cur][t];
  int ex = incl - d;
  if (i < N_NODES) {
    int rs = bsum[blockIdx.x] + ex;
    row_start[i] = rs;
    dinv[i] = rsqrtf((float)(d + 1));   // +1 self-loop
  }
  if (i == N_NODES) row_start[N_NODES] = E;
}

// ---------------- pass A: tile-staged bin scatter into fixed-capacity bin regions ----------------
__global__ __launch_bounds__(256) void k_binA(const int* __restrict__ src,
                                              const int* __restrict__ dst, int E,
                                              int* __restrict__ bincur,
                                              unsigned* __restrict__ binned) {
  __shared__ unsigned stage[TILE];
  __shared__ int cnt[NCBIN];
  __shared__ int loff[NCBIN + 1];
  __shared__ int goff[NCBIN];
  __shared__ int sc[2][256];
  const int tid = threadIdx.x;

  for (int i = tid; i < NCBIN; i += 256) cnt[i] = 0;
  __syncthreads();

  const int e0 = blockIdx.x * TILE;
  const int n = min(TILE, E - e0);

  unsigned pk[EPT];
  int bp[EPT];
#pragma unroll
  for (int i = 0; i < EPT; ++i) {
    int o = i * 256 + tid;
    if (o < n) {
      int e = e0 + o;
      int d = dst[e];
      int s = src[e];
      int b = d >> CBITS;
      pk[i] = (unsigned)s | ((unsigned)(d & (CNODES - 1)) << 17);
      int p = atomicAdd(&cnt[b], 1);
      bp[i] = b | (p << 9);             // b: 9 bits, p: <= 13 bits
    } else bp[i] = -1;
  }
  __syncthreads();

  // exclusive scan of cnt[391] (pairs -> Hillis-Steele over 256)
  int c0 = (2 * tid     < NCBIN) ? cnt[2 * tid]     : 0;
  int c1 = (2 * tid + 1 < NCBIN) ? cnt[2 * tid + 1] : 0;
  sc[0][tid] = c0 + c1;
  __syncthreads();
  int cur = 0;
#pragma unroll
  for (int off = 1; off < 256; off <<= 1) {
    sc[cur ^ 1][tid] = sc[cur][tid] + ((tid >= off) ? sc[cur][tid - off] : 0);
    __syncthreads();
    cur ^= 1;
  }
  int ex = sc[cur][tid] - (c0 + c1);
  if (2 * tid < NCBIN) loff[2 * tid] = ex;
  if (2 * tid + 1 < NCBIN) loff[2 * tid + 1] = ex + c0;
  if (tid == 255) loff[NCBIN] = sc[cur][255];
  __syncthreads();
  // reserve global space per bin
  for (int i = tid; i < NCBIN; i += 256)
    if (cnt[i] > 0) goff[i] = atomicAdd(&bincur[i], cnt[i]);
  __syncthreads();

  // scatter into LDS stage (bin-sorted within tile)
#pragma unroll
  for (int i = 0; i < EPT; ++i) {
    if (bp[i] >= 0) {
      int b = bp[i] & 511;
      int p = bp[i] >> 9;
      stage[loff[b] + p] = pk[i];
    }
  }
  __syncthreads();

  // linear copy-out: contiguous runs per bin
  for (int i = tid; i < n; i += 256) {
    int lo = 0, hi = NCBIN;
    while (hi - lo > 1) { int mid = (lo + hi) >> 1; if (loff[mid] <= i) lo = mid; else hi = mid; }
    int b = lo;
    binned[(size_t)b * BINCAP + goff[b] + (i - loff[b])] = stage[i];
  }
}

// ---------------- pass B1: per-bin degree count (LDS atomics, coalesced deg write) ----------------
__global__ __launch_bounds__(256) void k_binB1(const unsigned* __restrict__ binned,
                                               const int* __restrict__ bincur,
                                               int* __restrict__ deg) {
  __shared__ int lcnt[CNODES];
  int b = blockIdx.x;
  int t = threadIdx.x;
  lcnt[t] = 0;
  __syncthreads();
  int cnt = bincur[b];
  const unsigned* bp = binned + (size_t)b * BINCAP;
  for (int i = t; i < cnt; i += 256) {
    unsigned v = bp[i];
    atomicAdd(&lcnt[v >> 17], 1);
  }
  __syncthreads();
  int node = (b << CBITS) + t;
  if (node < N_NODES) deg[node] = lcnt[t];
}

// ---------------- pass B2: per-bin LDS-cursor sort -> coalesced csr_col write ----------------
__global__ __launch_bounds__(256) void k_binB2(const unsigned* __restrict__ binned,
                                               const int* __restrict__ bincur,
                                               const int* __restrict__ row_start,
                                               unsigned* __restrict__ csr_col) {
  __shared__ unsigned sortbuf[BINCAP];
  __shared__ int lcur[CNODES];
  int b = blockIdx.x;
  int t = threadIdx.x;
  int node0 = b << CBITS;
  int nodes = min(CNODES, N_NODES - node0);
  int rs0 = row_start[node0];
  if (t < nodes) lcur[t] = row_start[node0 + t] - rs0;
  __syncthreads();
  int cnt = bincur[b];
  const unsigned* bp = binned + (size_t)b * BINCAP;
  for (int i = t; i < cnt; i += 256) {
    unsigned v = bp[i];
    int p = atomicAdd(&lcur[v >> 17], 1);
    sortbuf[p] = v & 0x1FFFFu;
  }
  __syncthreads();
  for (int i = t; i < cnt; i += 256) csr_col[rs0 + i] = sortbuf[i];
}

// ---------------- fused MLP: x -> h0[N,4], zt0 = dinv*h0 ----------------
// x-tile register prefetch: next K-tile's loads issued before the MFMA phase.
__global__ __launch_bounds__(256, 2) void k_mlp(
    const float* __restrict__ x, const unsigned short* __restrict__ w1b,
    const unsigned short* __restrict__ w2b, const float* __restrict__ bias1,
    const float* __restrict__ bias2, const float* __restrict__ w3,
    const float* __restrict__ b3, const float* __restrict__ dinv,
    float4* __restrict__ h0, float4* __restrict__ zt) {
  __shared__ unsigned short arena[35840];
  __shared__ float lds_w3[384];
  unsigned short* lds_x = arena;
  unsigned short* lds_w = arena + 9216;
  unsigned short* lds_h = arena;
  unsigned short* lds_w2 = arena + 18432;

  const int tid = threadIdx.x;
  const int lane = tid & 63;
  const int wv = tid >> 6;
  const int fr = lane & 15;
  const int kq = (lane >> 4) * 8;
  const int rq = (lane >> 4) * 4;
  const int row0 = blockIdx.x * M_TILE;

  for (int i = tid; i < 384; i += 256) lds_w3[i] = w3[i];

#pragma unroll
  for (int it = 0; it < 8; ++it) {
    int idx = it * 256 + tid;
    int n = idx >> 4, c8 = idx & 15;
    uint4 v = *(const uint4*)(w2b + n * 128 + c8 * 8);
    *(uint4*)(lds_w2 + n * 136 + c8 * 8) = v;
  }

  f32x4 xr[8];
#pragma unroll
  for (int it = 0; it < 8; ++it) {
    int idx = it * 256 + tid;
    int r = idx >> 4, c4 = idx & 15;
    int gm = row0 + r;
    if (gm >= N_NODES) gm = N_NODES - 1;
    xr[it] = *(const f32x4*)(x + (size_t)gm * D_IN + 0 + c4 * 4);
  }

  f32x4 zero4 = {0.f, 0.f, 0.f, 0.f};
  f32x4 acc[2][8];
#pragma unroll
  for (int mt = 0; mt < 2; ++mt)
#pragma unroll
    for (int nt = 0; nt < 8; ++nt) acc[mt][nt] = zero4;

  for (int kb = 0; kb < D_IN; kb += BK) {
#pragma unroll
    for (int it = 0; it < 8; ++it) {
      int idx = it * 256 + tid;
      int r = idx >> 4, c4 = idx & 15;
      u16x4 o;
      o.x = f2bf(xr[it].x); o.y = f2bf(xr[it].y); o.z = f2bf(xr[it].z); o.w = f2bf(xr[it].w);
      *(u16x4*)(lds_x + r * 72 + c4 * 4) = o;
    }
#pragma unroll
    for (int it = 0; it < 4; ++it) {
      int idx = it * 256 + tid;
      int n = idx >> 3, c8 = idx & 7;
      uint4 v = *(const uint4*)(w1b + n * 512 + kb + c8 * 8);
      *(uint4*)(lds_w + n * 72 + c8 * 8) = v;
    }
    __syncthreads();
    if (kb + BK < D_IN) {
#pragma unroll
      for (int it = 0; it < 8; ++it) {
        int idx = it * 256 + tid;
        int r = idx >> 4, c4 = idx & 15;
        int gm = row0 + r;
        if (gm >= N_NODES) gm = N_NODES - 1;
        xr[it] = *(const f32x4*)(x + (size_t)gm * D_IN + (kb + BK) + c4 * 4);
      }
    }
#pragma unroll
    for (int kk = 0; kk < BK; kk += 32) {
      bf16x8 a[2], b[8];
#pragma unroll
      for (int mt = 0; mt < 2; ++mt)
        a[mt] = __builtin_bit_cast(bf16x8, *(const u16x8*)(lds_x + (wv * 32 + mt * 16 + fr) * 72 + kk + kq));
#pragma unroll
      for (int nt = 0; nt < 8; ++nt)
        b[nt] = __builtin_bit_cast(bf16x8, *(const u16x8*)(lds_w + (nt * 16 + fr) * 72 + kk + kq));
#pragma unroll
      for (int mt = 0; mt < 2; ++mt)
#pragma unroll
        for (int nt = 0; nt < 8; ++nt)
          acc[mt][nt] = __builtin_amdgcn_mfma_f32_16x16x32_bf16(a[mt], b[nt], acc[mt][nt], 0, 0, 0);
    }
    __syncthreads();
  }

  float b1v[8], b2v[8];
#pragma unroll
  for (int nt = 0; nt < 8; ++nt) {
    b1v[nt] = bias1[nt * 16 + fr];
    b2v[nt] = bias2[nt * 16 + fr];
  }
  float hr[2][8][4];
#pragma unroll
  for (int mt = 0; mt < 2; ++mt)
#pragma unroll
    for (int nt = 0; nt < 8; ++nt)
#pragma unroll
      for (int r = 0; r < 4; ++r) {
        int rl = wv * 32 + mt * 16 + rq + r;
        int cl = nt * 16 + fr;
        float h = acc[mt][nt][r] + b1v[nt];
        h = h > 0.f ? h : 0.f;
        hr[mt][nt][r] = h;
        lds_h[rl * 136 + cl] = f2bf(h);
      }
  __syncthreads();

  f32x4 acc2[2][8];
#pragma unroll
  for (int mt = 0; mt < 2; ++mt)
#pragma unroll
    for (int nt = 0; nt < 8; ++nt) acc2[mt][nt] = zero4;
#pragma unroll
  for (int kk = 0; kk < 128; kk += 32) {
    bf16x8 a[2], b[8];
#pragma unroll
    for (int mt = 0; mt < 2; ++mt)
      a[mt] = __builtin_bit_cast(bf16x8, *(const u16x8*)(lds_h + (wv * 32 + mt * 16 + fr) * 136 + kk + kq));
#pragma unroll
    for (int nt = 0; nt < 8; ++nt)
      b[nt] = __builtin_bit_cast(bf16x8, *(const u16x8*)(lds_w2 + (nt * 16 + fr) * 136 + kk + kq));
#pragma unroll
    for (int mt = 0; mt < 2; ++mt)
#pragma unroll
      for (int nt = 0; nt < 8; ++nt)
        acc2[mt][nt] = __builtin_amdgcn_mfma_f32_16x16x32_bf16(a[mt], b[nt], acc2[mt][nt], 0, 0, 0);
  }
  __syncthreads();

#pragma unroll
  for (int mt = 0; mt < 2; ++mt)
#pragma unroll
    for (int nt = 0; nt < 8; ++nt)
#pragma unroll
      for (int r = 0; r < 4; ++r) {
        int rl = wv * 32 + mt * 16 + rq + r;
        int cl = nt * 16 + fr;
        float t2 = acc2[mt][nt][r] + b2v[nt];
        t2 = t2 > 0.f ? t2 : 0.f;
        lds_h[rl * 136 + cl] = f2bf(hr[mt][nt][r] + t2);
      }
  __syncthreads();

  if (tid < 128) {
    int m = tid;
    int gm = row0 + m;
    if (gm < N_NODES) {
      float a0 = 0.f, a1 = 0.f, a2 = 0.f;
#pragma unroll 8
      for (int c = 0; c < 128; ++c) {
        float hv = bf2f(lds_h[m * 136 + c]);
        a0 += hv * lds_w3[c];
        a1 += hv * lds_w3[128 + c];
        a2 += hv * lds_w3[256 + c];
      }
      float z0 = a0 + b3[0], z1 = a1 + b3[1], z2 = a2 + b3[2];
      float di = dinv[gm];
      h0[gm] = make_float4(z0, z1, z2, 0.f);
      zt[gm] = make_float4(di * z0, di * z1, di * z2, 0.f);
    }
  }
}

// ---------------- one APPNP iteration: edge-parallel segmented reduction ----------------
// Block owns 64 nodes + their contiguous edge slice (LDS-staged). Every thread
// processes exactly ceil(cnt/256) consecutive edges -> zero wave-level imbalance
// (cnt is block-uniform). Row boundaries: binary search over LDS row_off[65] +
// rare LDS float atomic flushes (ds_add_f32, ~2/thread). Gather values preloaded
// into a statically-indexed 12xfloat4 register array (all loads in flight first).
template <bool FINAL>
__global__ __launch_bounds__(256) void k_iter3(
    const float4* __restrict__ zin, float4* __restrict__ zout,
    const int* __restrict__ row_start, const unsigned* __restrict__ csr_col,
    const float* __restrict__ dinv, const float4* __restrict__ h0v,
    float* __restrict__ out) {
  __shared__ unsigned lidx[LCAP3];
  __shared__ int row_off[NPB + 1];     // absolute row_start values
  __shared__ float accs[NPB][3];
  const int t = threadIdx.x;
  const int node0 = blockIdx.x * NPB;
  const int node = node0 + t;          // only meaningful for t < NPB

  if (t <= NPB) row_off[t] = row_start[min(node0 + t, N_NODES)];
  if (t < NPB) { accs[t][0] = 0.f; accs[t][1] = 0.f; accs[t][2] = 0.f; }
  __syncthreads();
  const int rs0 = row_off[0];
  const int cnt = row_off[NPB] - rs0;

  if (cnt <= LCAP3) {
    for (int i = t; i < cnt; i += 256) lidx[i] = csr_col[rs0 + i];
    __syncthreads();

    const int per = (cnt + 255) >> 8;      // <= PMAX
    const int e0 = t * per;
    const int e1 = min(e0 + per, cnt);
    if (e0 < e1) {
      // preload gather values (static reg indexing; all loads issued up front)
      f32x4 v[PMAX];
#pragma unroll
      for (int i = 0; i < PMAX; ++i) {
        int e = e0 + i;
        unsigned c = lidx[(e < e1) ? e : (e1 - 1)];
        v[i] = *(const f32x4*)(zin + c);
      }
      // binary search row containing e0 (largest r with row_off[r]-rs0 <= e0)
      int lo = 0, hi = NPB;
      while (hi - lo > 1) {
        int m = (lo + hi) >> 1;
        if (row_off[m] - rs0 <= e0) lo = m; else hi = m;
      }
      int r = lo;
      int nb = row_off[r + 1] - rs0;
      float sx = 0.f, sy = 0.f, sz = 0.f;
#pragma unroll
      for (int i = 0; i < PMAX; ++i) {
        int e = e0 + i;
        if (e < e1) {
          while (e >= nb) {            // flush row r, advance (skips empty rows)
            atomicAdd(&accs[r][0], sx);
            atomicAdd(&accs[r][1], sy);
            atomicAdd(&accs[r][2], sz);
            sx = 0.f; sy = 0.f; sz = 0.f;
            ++r;
            nb = row_off[r + 1] - rs0;
          }
          sx += v[i].x; sy += v[i].y; sz += v[i].z;
        }
      }
      atomicAdd(&accs[r][0], sx);
      atomicAdd(&accs[r][1], sy);
      atomicAdd(&accs[r][2], sz);
    }
  } else {
    // improbable fallback (cnt > LCAP3): node-per-thread, global indices
    if (t < NPB && node < N_NODES) {
      int r0 = row_start[node], r1 = row_start[node + 1];
      float sx = 0.f, sy = 0.f, sz = 0.f;
      for (int j = r0; j < r1; ++j) {
        float4 vv = zin[csr_col[j]];
        sx += vv.x; sy += vv.y; sz += vv.z;
      }
      accs[t][0] = sx; accs[t][1] = sy; accs[t][2] = sz;
    }
  }
  __syncthreads();

  if (t < NPB && node < N_NODES) {
    float4 self = zin[node];
    float4 h = h0v[node];
    float di = dinv[node];
    float sx = accs[t][0] + self.x;
    float sy = accs[t][1] + self.y;
    float sz = accs[t][2] + self.z;
    float zx = (1.f - ALPHA) * di * sx + ALPHA * h.x;
    float zy = (1.f - ALPHA) * di * sy + ALPHA * h.y;
    float zz = (1.f - ALPHA) * di * sz + ALPHA * h.z;
    if (!FINAL) {
      zout[node] = make_float4(di * zx, di * zy, di * zz, 0.f);
    } else {
      float mx = fmaxf(zx, fmaxf(zy, zz));
      float l = logf(expf(zx - mx) + expf(zy - mx) + expf(zz - mx));
      out[node * 3 + 0] = zx - mx - l;
      out[node * 3 + 1] = zy - mx - l;
      out[node * 3 + 2] = zz - mx - l;
    }
  }
}

extern "C" void kernel_launch(void* const* d_in, const int* in_sizes, int n_in,
                              void* d_out, int out_size, void* d_ws, size_t ws_size,
                              hipStream_t stream) {
  const float* x   = (const float*)d_in[0];
  const int*   ei  = (const int*)d_in[1];
  const float* w1  = (const float*)d_in[2];
  const float* b1  = (const float*)d_in[3];
  const float* g1  = (const float*)d_in[4];
  const float* be1 = (const float*)d_in[5];
  const float* m1  = (const float*)d_in[6];
  const float* v1  = (const float*)d_in[7];
  const float* w2  = (const float*)d_in[8];
  const float* b2  = (const float*)d_in[9];
  const float* g2  = (const float*)d_in[10];
  const float* be2 = (const float*)d_in[11];
  const float* m2  = (const float*)d_in[12];
  const float* v2  = (const float*)d_in[13];
  const float* w3  = (const float*)d_in[14];
  const float* b3  = (const float*)d_in[15];

  const int E = in_sizes[1] / 2;
  const int* srcA = ei;
  const int* dstA = ei + E;

  char* w = (char*)d_ws;
  size_t off = 0;
  auto alloc = [&](size_t bytes) -> void* {
    void* p = w + off;
    off = (off + bytes + 255) & ~(size_t)255;
    return p;
  };
  unsigned short* w1b   = (unsigned short*)alloc(65536 * 2);
  unsigned short* w2b   = (unsigned short*)alloc(16384 * 2);
  float* bias1          = (float*)alloc(128 * 4);
  float* bias2          = (float*)alloc(128 * 4);
  int*   deg            = (int*)alloc((size_t)N_NODES * 4);
  int*   row_start      = (int*)alloc(((size_t)N_NODES + 1) * 4);
  float* dinv           = (float*)alloc((size_t)N_NODES * 4);
  int*   bsum           = (int*)alloc(512 * 4);
  int*   bincur         = (int*)alloc((size_t)NCBIN * 4);
  float4* h0            = (float4*)alloc((size_t)N_NODES * 16);
  float4* ztA           = (float4*)alloc((size_t)N_NODES * 16);
  float4* ztB           = (float4*)alloc((size_t)N_NODES * 16);
  unsigned* csr_col     = (unsigned*)alloc((size_t)E * 4);
  unsigned* binned      = (unsigned*)alloc((size_t)NCBIN * BINCAP * 4);

  const int NB = (N_NODES + 255) / 256;        // 391
  const int NTILE = (E + TILE - 1) / TILE;     // 391 for E=3.2M

  k_prep<<<(82176 + NCBIN + 255) / 256, 256, 0, stream>>>(
      w1, b1, g1, be1, m1, v1, w2, b2, g2, be2, m2, v2, w1b, w2b, bias1, bias2, bincur);
  k_binA<<<NTILE, 256, 0, stream>>>(srcA, dstA, E, bincur, binned);
  k_binB1<<<NCBIN, 256, 0, stream>>>(binned, bincur, deg);
  k_scan2<<<1, 256, 0, stream>>>(bincur, bsum);     // bsum[b] = exclusive scan of bincur
  k_scan3<<<NB, 256, 0, stream>>>(deg, bsum, row_start, dinv, E);
  k_binB2<<<NCBIN, 256, 0, stream>>>(binned, bincur, row_start, csr_col);
  k_mlp<<<(N_NODES + M_TILE - 1) / M_TILE, 256, 0, stream>>>(
      x, w1b, w2b, bias1, bias2, w3, b3, dinv, h0, ztA);

  const float4* zin = ztA;
  float4* zout = ztB;
  for (int k = 0; k < 9; ++k) {
    k_iter3<false><<<NB2, 256, 0, stream>>>(zin, zout, row_start, csr_col, dinv, h0, nullptr);
    const float4* tswap = zout;
    zout = (float4*)zin;
    zin = tswap;
  }
  k_iter3<true><<<NB2, 256, 0, stream>>>(zin, nullptr, row_start, csr_col, dinv, h0, (float*)d_out);
}

// Round 9
// 572.512 us; speedup vs baseline: 1.1668x; 1.1668x over previous
//
#include <hip/hip_runtime.h>
#include <cstdint>
#include <cstddef>

#define N_NODES 100000
#define D_IN 512
#define ALPHA 0.1f
#define EPS_BN 1e-5f
#define M_TILE 128
#define BK 64

// ---- CSR build: 256-node bins, tile-staged counting sort ----
#define CBITS 8
#define CNODES 256
#define NCBIN 391            // ceil(100000/256)
#define TILE 8192
#define EPT 32               // edges per thread (256 threads * 32 = 8192)
#define BINCAP 9216          // per-bin fixed capacity (mean 8192 + 11 sigma)

// ---- propagation: 4 threads/node, LDS-staged indices, 8B packed zt ----
#define NPB 64               // nodes per block (4 threads/node, 256 threads)
#define NB2 1563             // ceil(100000/64)
#define LCAP3 3072           // index slice capacity (mean 2048 + ~22 sigma)

typedef float f32x4 __attribute__((ext_vector_type(4)));
typedef __bf16 bf16x8 __attribute__((ext_vector_type(8)));
typedef unsigned short u16x8 __attribute__((ext_vector_type(8)));
typedef unsigned short u16x4 __attribute__((ext_vector_type(4)));
typedef unsigned long long u64;

__device__ __forceinline__ unsigned short f2bf(float f) {
  unsigned u = __float_as_uint(f);
  u += 0x7fffu + ((u >> 16) & 1u);   // RNE
  return (unsigned short)(u >> 16);
}
__device__ __forceinline__ float bf2f(unsigned short h) {
  return __uint_as_float(((unsigned)h) << 16);
}

// zt packed as 3xf16 in 8B: halves gather width (dwordx2 vs dwordx4).
__device__ __forceinline__ u64 pk3(float x, float y, float z) {
  unsigned short a = __builtin_bit_cast(unsigned short, (_Float16)x);  // RNE
  unsigned short b = __builtin_bit_cast(unsigned short, (_Float16)y);
  unsigned short c = __builtin_bit_cast(unsigned short, (_Float16)z);
  return (u64)a | ((u64)b << 16) | ((u64)c << 32);
}
__device__ __forceinline__ void up3(u64 p, float& sx, float& sy, float& sz) {
  unsigned lo = (unsigned)p, hi = (unsigned)(p >> 32);
  sx += (float)__builtin_bit_cast(_Float16, (unsigned short)(lo & 0xFFFFu));
  sy += (float)__builtin_bit_cast(_Float16, (unsigned short)(lo >> 16));
  sz += (float)__builtin_bit_cast(_Float16, (unsigned short)(hi & 0xFFFFu));
}

// ---------------- prep: fold BN into weights (bf16) + biases, zero bin cursors ----------------
__global__ void k_prep(const float* __restrict__ w1, const float* __restrict__ b1,
                       const float* __restrict__ g1, const float* __restrict__ be1,
                       const float* __restrict__ m1, const float* __restrict__ v1,
                       const float* __restrict__ w2, const float* __restrict__ b2,
                       const float* __restrict__ g2, const float* __restrict__ be2,
                       const float* __restrict__ m2, const float* __restrict__ v2,
                       unsigned short* __restrict__ w1b, unsigned short* __restrict__ w2b,
                       float* __restrict__ bias1, float* __restrict__ bias2,
                       int* __restrict__ bincur) {
  int idx = blockIdx.x * 256 + threadIdx.x;
  if (idx < 65536) {                       // w1: [128][512], scale row n by s1[n]
    int n = idx >> 9;
    float s = g1[n] * rsqrtf(v1[n] + EPS_BN);
    w1b[idx] = f2bf(w1[idx] * s);
  } else if (idx < 81920) {                // w2: [128][128]
    int i = idx - 65536;
    int n = i >> 7;
    float s = g2[n] * rsqrtf(v2[n] + EPS_BN);
    w2b[i] = f2bf(w2[i] * s);
  } else if (idx < 82048) {
    int c = idx - 81920;
    float s = g1[c] * rsqrtf(v1[c] + EPS_BN);
    bias1[c] = (b1[c] - m1[c]) * s + be1[c];
  } else if (idx < 82176) {
    int c = idx - 82048;
    float s = g2[c] * rsqrtf(v2[c] + EPS_BN);
    bias2[c] = (b2[c] - m2[c]) * s + be2[c];
  }
  int bi = idx - 82176;
  if (bi >= 0 && bi < NCBIN) bincur[bi] = 0;
}

// ---------------- pass A: tile-staged bin scatter into fixed-capacity bin regions ----------------
__global__ __launch_bounds__(256) void k_binA(const int* __restrict__ src,
                                              const int* __restrict__ dst, int E,
                                              int* __restrict__ bincur,
                                              unsigned* __restrict__ binned) {
  __shared__ unsigned stage[TILE];
  __shared__ int cnt[NCBIN];
  __shared__ int loff[NCBIN + 1];
  __shared__ int goff[NCBIN];
  __shared__ int sc[2][256];
  const int tid = threadIdx.x;

  for (int i = tid; i < NCBIN; i += 256) cnt[i] = 0;
  __syncthreads();

  const int e0 = blockIdx.x * TILE;
  const int n = min(TILE, E - e0);

  unsigned pk[EPT];
  int bp[EPT];
#pragma unroll
  for (int i = 0; i < EPT; ++i) {
    int o = i * 256 + tid;
    if (o < n) {
      int e = e0 + o;
      int d = dst[e];
      int s = src[e];
      int b = d >> CBITS;
      pk[i] = (unsigned)s | ((unsigned)(d & (CNODES - 1)) << 17);
      int p = atomicAdd(&cnt[b], 1);
      bp[i] = b | (p << 9);             // b: 9 bits, p: <= 13 bits
    } else bp[i] = -1;
  }
  __syncthreads();

  // exclusive scan of cnt[391] (pairs -> Hillis-Steele over 256)
  int c0 = (2 * tid     < NCBIN) ? cnt[2 * tid]     : 0;
  int c1 = (2 * tid + 1 < NCBIN) ? cnt[2 * tid + 1] : 0;
  sc[0][tid] = c0 + c1;
  __syncthreads();
  int cur = 0;
#pragma unroll
  for (int off = 1; off < 256; off <<= 1) {
    sc[cur ^ 1][tid] = sc[cur][tid] + ((tid >= off) ? sc[cur][tid - off] : 0);
    __syncthreads();
    cur ^= 1;
  }
  int ex = sc[cur][tid] - (c0 + c1);
  if (2 * tid < NCBIN) loff[2 * tid] = ex;
  if (2 * tid + 1 < NCBIN) loff[2 * tid + 1] = ex + c0;
  if (tid == 255) loff[NCBIN] = sc[cur][255];
  __syncthreads();
  // reserve global space per bin
  for (int i = tid; i < NCBIN; i += 256)
    if (cnt[i] > 0) goff[i] = atomicAdd(&bincur[i], cnt[i]);
  __syncthreads();

  // scatter into LDS stage (bin-sorted within tile)
#pragma unroll
  for (int i = 0; i < EPT; ++i) {
    if (bp[i] >= 0) {
      int b = bp[i] & 511;
      int p = bp[i] >> 9;
      stage[loff[b] + p] = pk[i];
    }
  }
  __syncthreads();

  // linear copy-out: contiguous runs per bin
  for (int i = tid; i < n; i += 256) {
    int lo = 0, hi = NCBIN;
    while (hi - lo > 1) { int mid = (lo + hi) >> 1; if (loff[mid] <= i) lo = mid; else hi = mid; }
    int b = lo;
    binned[(size_t)b * BINCAP + goff[b] + (i - loff[b])] = stage[i];
  }
}

// ---------------- fused pass B: count + scan + row_start/dinv + sort (one kernel) ----------------
// One block per bin. rs0 computed by direct reduction of bincur[0..b) (391 ints, trivial).
// Replaces k_binB1 + k_scan2 + k_scan3 + k_binB2: one binned read instead of two,
// 3 fewer launches, no deg/bsum round-trips.
__global__ __launch_bounds__(256) void k_binB(const unsigned* __restrict__ binned,
                                              const int* __restrict__ bincur,
                                              int* __restrict__ row_start,
                                              float* __restrict__ dinv,
                                              unsigned* __restrict__ csr_col, int E) {
  __shared__ unsigned ebuf[BINCAP];
  __shared__ unsigned sortbuf[BINCAP];
  __shared__ int lcnt[CNODES];
  __shared__ int lcur[CNODES];
  __shared__ int sb[2][256];
  __shared__ int red[4];
  const int b = blockIdx.x;
  const int t = threadIdx.x;

  // rs0 = sum of bincur[0..b)
  int part = 0;
  for (int i = t; i < b; i += 256) part += bincur[i];
#pragma unroll
  for (int off = 32; off > 0; off >>= 1) part += __shfl_down(part, off, 64);
  if ((t & 63) == 0) red[t >> 6] = part;
  lcnt[t] = 0;
  __syncthreads();
  const int rs0 = (red[0] + red[1]) + (red[2] + red[3]);
  int cnt = bincur[b];
  if (cnt > BINCAP) cnt = BINCAP;

  // read binned slice once into LDS + count degrees
  const unsigned* bp = binned + (size_t)b * BINCAP;
  for (int i = t; i < cnt; i += 256) {
    unsigned v = bp[i];
    ebuf[i] = v;
    atomicAdd(&lcnt[v >> 17], 1);
  }
  __syncthreads();

  // exclusive scan of lcnt[256]
  sb[0][t] = lcnt[t];
  __syncthreads();
  int cur = 0;
#pragma unroll
  for (int off = 1; off < 256; off <<= 1) {
    sb[cur ^ 1][t] = sb[cur][t] + ((t >= off) ? sb[cur][t - off] : 0);
    __syncthreads();
    cur ^= 1;
  }
  int ex = sb[cur][t] - lcnt[t];

  const int node0 = b << CBITS;
  const int node = node0 + t;
  if (node < N_NODES) {
    row_start[node] = rs0 + ex;
    dinv[node] = rsqrtf((float)(lcnt[t] + 1));   // +1 self-loop
  }
  if (node == N_NODES) row_start[N_NODES] = E;
  if (b == NCBIN - 1 && t == 255) row_start[N_NODES] = E;  // nodes==256 case safety
  lcur[t] = ex;
  __syncthreads();

  // LDS-cursor sort -> coalesced csr_col write
  for (int i = t; i < cnt; i += 256) {
    unsigned v = ebuf[i];
    int p = atomicAdd(&lcur[v >> 17], 1);
    sortbuf[p] = v & 0x1FFFFu;
  }
  __syncthreads();
  for (int i = t; i < cnt; i += 256) csr_col[rs0 + i] = sortbuf[i];
}

// ---------------- fused MLP: x -> h0[N,4], zt0 = pk3(dinv*h0) ----------------
__global__ __launch_bounds__(256, 2) void k_mlp(
    const float* __restrict__ x, const unsigned short* __restrict__ w1b,
    const unsigned short* __restrict__ w2b, const float* __restrict__ bias1,
    const float* __restrict__ bias2, const float* __restrict__ w3,
    const float* __restrict__ b3, const float* __restrict__ dinv,
    float4* __restrict__ h0, u64* __restrict__ zt) {
  __shared__ unsigned short arena[35840];
  __shared__ float lds_w3[384];
  unsigned short* lds_x = arena;
  unsigned short* lds_w = arena + 9216;
  unsigned short* lds_h = arena;
  unsigned short* lds_w2 = arena + 18432;

  const int tid = threadIdx.x;
  const int lane = tid & 63;
  const int wv = tid >> 6;
  const int fr = lane & 15;
  const int kq = (lane >> 4) * 8;
  const int rq = (lane >> 4) * 4;
  const int row0 = blockIdx.x * M_TILE;

  for (int i = tid; i < 384; i += 256) lds_w3[i] = w3[i];

#pragma unroll
  for (int it = 0; it < 8; ++it) {
    int idx = it * 256 + tid;
    int n = idx >> 4, c8 = idx & 15;
    uint4 v = *(const uint4*)(w2b + n * 128 + c8 * 8);
    *(uint4*)(lds_w2 + n * 136 + c8 * 8) = v;
  }

  f32x4 xr[8];
#pragma unroll
  for (int it = 0; it < 8; ++it) {
    int idx = it * 256 + tid;
    int r = idx >> 4, c4 = idx & 15;
    int gm = row0 + r;
    if (gm >= N_NODES) gm = N_NODES - 1;
    xr[it] = *(const f32x4*)(x + (size_t)gm * D_IN + 0 + c4 * 4);
  }

  f32x4 zero4 = {0.f, 0.f, 0.f, 0.f};
  f32x4 acc[2][8];
#pragma unroll
  for (int mt = 0; mt < 2; ++mt)
#pragma unroll
    for (int nt = 0; nt < 8; ++nt) acc[mt][nt] = zero4;

  for (int kb = 0; kb < D_IN; kb += BK) {
#pragma unroll
    for (int it = 0; it < 8; ++it) {
      int idx = it * 256 + tid;
      int r = idx >> 4, c4 = idx & 15;
      u16x4 o;
      o.x = f2bf(xr[it].x); o.y = f2bf(xr[it].y); o.z = f2bf(xr[it].z); o.w = f2bf(xr[it].w);
      *(u16x4*)(lds_x + r * 72 + c4 * 4) = o;
    }
#pragma unroll
    for (int it = 0; it < 4; ++it) {
      int idx = it * 256 + tid;
      int n = idx >> 3, c8 = idx & 7;
      uint4 v = *(const uint4*)(w1b + n * 512 + kb + c8 * 8);
      *(uint4*)(lds_w + n * 72 + c8 * 8) = v;
    }
    __syncthreads();
    if (kb + BK < D_IN) {
#pragma unroll
      for (int it = 0; it < 8; ++it) {
        int idx = it * 256 + tid;
        int r = idx >> 4, c4 = idx & 15;
        int gm = row0 + r;
        if (gm >= N_NODES) gm = N_NODES - 1;
        xr[it] = *(const f32x4*)(x + (size_t)gm * D_IN + (kb + BK) + c4 * 4);
      }
    }
#pragma unroll
    for (int kk = 0; kk < BK; kk += 32) {
      bf16x8 a[2], b[8];
#pragma unroll
      for (int mt = 0; mt < 2; ++mt)
        a[mt] = __builtin_bit_cast(bf16x8, *(const u16x8*)(lds_x + (wv * 32 + mt * 16 + fr) * 72 + kk + kq));
#pragma unroll
      for (int nt = 0; nt < 8; ++nt)
        b[nt] = __builtin_bit_cast(bf16x8, *(const u16x8*)(lds_w + (nt * 16 + fr) * 72 + kk + kq));
#pragma unroll
      for (int mt = 0; mt < 2; ++mt)
#pragma unroll
        for (int nt = 0; nt < 8; ++nt)
          acc[mt][nt] = __builtin_amdgcn_mfma_f32_16x16x32_bf16(a[mt], b[nt], acc[mt][nt], 0, 0, 0);
    }
    __syncthreads();
  }

  float b1v[8], b2v[8];
#pragma unroll
  for (int nt = 0; nt < 8; ++nt) {
    b1v[nt] = bias1[nt * 16 + fr];
    b2v[nt] = bias2[nt * 16 + fr];
  }
  float hr[2][8][4];
#pragma unroll
  for (int mt = 0; mt < 2; ++mt)
#pragma unroll
    for (int nt = 0; nt < 8; ++nt)
#pragma unroll
      for (int r = 0; r < 4; ++r) {
        int rl = wv * 32 + mt * 16 + rq + r;
        int cl = nt * 16 + fr;
        float h = acc[mt][nt][r] + b1v[nt];
        h = h > 0.f ? h : 0.f;
        hr[mt][nt][r] = h;
        lds_h[rl * 136 + cl] = f2bf(h);
      }
  __syncthreads();

  f32x4 acc2[2][8];
#pragma unroll
  for (int mt = 0; mt < 2; ++mt)
#pragma unroll
    for (int nt = 0; nt < 8; ++nt) acc2[mt][nt] = zero4;
#pragma unroll
  for (int kk = 0; kk < 128; kk += 32) {
    bf16x8 a[2], b[8];
#pragma unroll
    for (int mt = 0; mt < 2; ++mt)
      a[mt] = __builtin_bit_cast(bf16x8, *(const u16x8*)(lds_h + (wv * 32 + mt * 16 + fr) * 136 + kk + kq));
#pragma unroll
    for (int nt = 0; nt < 8; ++nt)
      b[nt] = __builtin_bit_cast(bf16x8, *(const u16x8*)(lds_w2 + (nt * 16 + fr) * 136 + kk + kq));
#pragma unroll
    for (int mt = 0; mt < 2; ++mt)
#pragma unroll
      for (int nt = 0; nt < 8; ++nt)
        acc2[mt][nt] = __builtin_amdgcn_mfma_f32_16x16x32_bf16(a[mt], b[nt], acc2[mt][nt], 0, 0, 0);
  }
  __syncthreads();

#pragma unroll
  for (int mt = 0; mt < 2; ++mt)
#pragma unroll
    for (int nt = 0; nt < 8; ++nt)
#pragma unroll
      for (int r = 0; r < 4; ++r) {
        int rl = wv * 32 + mt * 16 + rq + r;
        int cl = nt * 16 + fr;
        float t2 = acc2[mt][nt][r] + b2v[nt];
        t2 = t2 > 0.f ? t2 : 0.f;
        lds_h[rl * 136 + cl] = f2bf(hr[mt][nt][r] + t2);
      }
  __syncthreads();

  if (tid < 128) {
    int m = tid;
    int gm = row0 + m;
    if (gm < N_NODES) {
      float a0 = 0.f, a1 = 0.f, a2 = 0.f;
#pragma unroll 8
      for (int c = 0; c < 128; ++c) {
        float hv = bf2f(lds_h[m * 136 + c]);
        a0 += hv * lds_w3[c];
        a1 += hv * lds_w3[128 + c];
        a2 += hv * lds_w3[256 + c];
      }
      float z0 = a0 + b3[0], z1 = a1 + b3[1], z2 = a2 + b3[2];
      float di = dinv[gm];
      h0[gm] = make_float4(z0, z1, z2, 0.f);
      zt[gm] = pk3(di * z0, di * z1, di * z2);
    }
  }
}

// ---------------- one APPNP iteration (4 threads/node, LDS idx, 8B packed gathers) ----------------
#define GATHER_BODY(IDX)                                                        \
  for (; j + 8 <= je; j += 8) {                                                 \
    u64 p0 = zin[IDX(j + 0)], p1 = zin[IDX(j + 1)];                             \
    u64 p2 = zin[IDX(j + 2)], p3 = zin[IDX(j + 3)];                             \
    u64 p4 = zin[IDX(j + 4)], p5 = zin[IDX(j + 5)];                             \
    u64 p6 = zin[IDX(j + 6)], p7 = zin[IDX(j + 7)];                             \
    up3(p0, sx, sy, sz); up3(p1, sx, sy, sz);                                   \
    up3(p2, sx, sy, sz); up3(p3, sx, sy, sz);                                   \
    up3(p4, sx, sy, sz); up3(p5, sx, sy, sz);                                   \
    up3(p6, sx, sy, sz); up3(p7, sx, sy, sz);                                   \
  }                                                                             \
  if (j + 4 <= je) {                                                            \
    u64 p0 = zin[IDX(j + 0)], p1 = zin[IDX(j + 1)];                             \
    u64 p2 = zin[IDX(j + 2)], p3 = zin[IDX(j + 3)];                             \
    up3(p0, sx, sy, sz); up3(p1, sx, sy, sz);                                   \
    up3(p2, sx, sy, sz); up3(p3, sx, sy, sz);                                   \
    j += 4;                                                                     \
  }                                                                             \
  if (j + 2 <= je) {                                                            \
    u64 p0 = zin[IDX(j + 0)], p1 = zin[IDX(j + 1)];                             \
    up3(p0, sx, sy, sz); up3(p1, sx, sy, sz);                                   \
    j += 2;                                                                     \
  }                                                                             \
  if (j < je) { u64 p0 = zin[IDX(j)]; up3(p0, sx, sy, sz); }

template <bool FINAL>
__global__ __launch_bounds__(256) void k_iter2(
    const u64* __restrict__ zin, u64* __restrict__ zout,
    const int* __restrict__ row_start, const unsigned* __restrict__ csr_col,
    const float* __restrict__ dinv, const float4* __restrict__ h0v,
    float* __restrict__ out) {
  __shared__ unsigned lidx[LCAP3];
  __shared__ float psum[3][NPB][3];
  __shared__ int srs[2];
  const int t = threadIdx.x;
  const int q = t >> 6;             // wave index = quarter of the row
  const int tn = t & 63;
  const int node0 = blockIdx.x * NPB;
  const int node = node0 + tn;
  const bool valid = node < N_NODES;

  if (t == 0) srs[0] = row_start[node0];
  if (t == 1) srs[1] = row_start[min(node0 + NPB, N_NODES)];
  __syncthreads();
  const int rs0 = srs[0];
  const int cnt = srs[1] - rs0;
  const bool use_lds = (cnt <= LCAP3);
  if (use_lds) {
    for (int i = t; i < cnt; i += 256) lidx[i] = csr_col[rs0 + i];
  }

  int jb = 0, je = 0;
  if (valid) {
    int r0 = row_start[node];
    int r1 = row_start[node + 1];
    int len = r1 - r0;
    jb = r0 + ((len * q) >> 2);
    je = r0 + ((len * (q + 1)) >> 2);
  }
  __syncthreads();

  float sx = 0.f, sy = 0.f, sz = 0.f;
  if (use_lds) {
    int j = jb - rs0;
    je -= rs0;
#define IDXL(J) lidx[J]
    GATHER_BODY(IDXL)
#undef IDXL
  } else {
    int j = jb;
#define IDXG(J) csr_col[J]
    GATHER_BODY(IDXG)
#undef IDXG
  }

  if (q) { psum[q - 1][tn][0] = sx; psum[q - 1][tn][1] = sy; psum[q - 1][tn][2] = sz; }
  __syncthreads();
  if (q == 0 && valid) {
    up3(zin[node], sx, sy, sz);       // self-loop term
    float4 h = h0v[node];
    float di = dinv[node];
    sx += (psum[0][tn][0] + psum[1][tn][0]) + psum[2][tn][0];
    sy += (psum[0][tn][1] + psum[1][tn][1]) + psum[2][tn][1];
    sz += (psum[0][tn][2] + psum[1][tn][2]) + psum[2][tn][2];
    float zx = (1.f - ALPHA) * di * sx + ALPHA * h.x;
    float zy = (1.f - ALPHA) * di * sy + ALPHA * h.y;
    float zz = (1.f - ALPHA) * di * sz + ALPHA * h.z;
    if (!FINAL) {
      zout[node] = pk3(di * zx, di * zy, di * zz);
    } else {
      float mx = fmaxf(zx, fmaxf(zy, zz));
      float l = logf(expf(zx - mx) + expf(zy - mx) + expf(zz - mx));
      out[node * 3 + 0] = zx - mx - l;
      out[node * 3 + 1] = zy - mx - l;
      out[node * 3 + 2] = zz - mx - l;
    }
  }
}

extern "C" void kernel_launch(void* const* d_in, const int* in_sizes, int n_in,
                              void* d_out, int out_size, void* d_ws, size_t ws_size,
                              hipStream_t stream) {
  const float* x   = (const float*)d_in[0];
  const int*   ei  = (const int*)d_in[1];
  const float* w1  = (const float*)d_in[2];
  const float* b1  = (const float*)d_in[3];
  const float* g1  = (const float*)d_in[4];
  const float* be1 = (const float*)d_in[5];
  const float* m1  = (const float*)d_in[6];
  const float* v1  = (const float*)d_in[7];
  const float* w2  = (const float*)d_in[8];
  const float* b2  = (const float*)d_in[9];
  const float* g2  = (const float*)d_in[10];
  const float* be2 = (const float*)d_in[11];
  const float* m2  = (const float*)d_in[12];
  const float* v2  = (const float*)d_in[13];
  const float* w3  = (const float*)d_in[14];
  const float* b3  = (const float*)d_in[15];

  const int E = in_sizes[1] / 2;
  const int* srcA = ei;
  const int* dstA = ei + E;

  char* w = (char*)d_ws;
  size_t off = 0;
  auto alloc = [&](size_t bytes) -> void* {
    void* p = w + off;
    off = (off + bytes + 255) & ~(size_t)255;
    return p;
  };
  unsigned short* w1b   = (unsigned short*)alloc(65536 * 2);
  unsigned short* w2b   = (unsigned short*)alloc(16384 * 2);
  float* bias1          = (float*)alloc(128 * 4);
  float* bias2          = (float*)alloc(128 * 4);
  int*   row_start      = (int*)alloc(((size_t)N_NODES + 1) * 4);
  float* dinv           = (float*)alloc((size_t)N_NODES * 4);
  int*   bincur         = (int*)alloc((size_t)NCBIN * 4);
  float4* h0            = (float4*)alloc((size_t)N_NODES * 16);
  u64*   ztA            = (u64*)alloc((size_t)N_NODES * 8);
  u64*   ztB            = (u64*)alloc((size_t)N_NODES * 8);
  unsigned* csr_col     = (unsigned*)alloc((size_t)E * 4);
  unsigned* binned      = (unsigned*)alloc((size_t)NCBIN * BINCAP * 4);

  const int NTILE = (E + TILE - 1) / TILE;     // 391 for E=3.2M

  k_prep<<<(82176 + NCBIN + 255) / 256, 256, 0, stream>>>(
      w1, b1, g1, be1, m1, v1, w2, b2, g2, be2, m2, v2, w1b, w2b, bias1, bias2, bincur);
  k_binA<<<NTILE, 256, 0, stream>>>(srcA, dstA, E, bincur, binned);
  k_binB<<<NCBIN, 256, 0, stream>>>(binned, bincur, row_start, dinv, csr_col, E);
  k_mlp<<<(N_NODES + M_TILE - 1) / M_TILE, 256, 0, stream>>>(
      x, w1b, w2b, bias1, bias2, w3, b3, dinv, h0, ztA);

  const u64* zin = ztA;
  u64* zout = ztB;
  for (int k = 0; k < 9; ++k) {
    k_iter2<false><<<NB2, 256, 0, stream>>>(zin, zout, row_start, csr_col, dinv, h0, nullptr);
    const u64* tswap = zout;
    zout = (u64*)zin;
    zin = tswap;
  }
  k_iter2<true><<<NB2, 256, 0, stream>>>(zin, nullptr, row_start, csr_col, dinv, h0, (float*)d_out);
}

// Round 10
// 557.941 us; speedup vs baseline: 1.1973x; 1.0261x over previous
//
#include <hip/hip_runtime.h>
#include <cstdint>
#include <cstddef>

#define N_NODES 100000
#define D_IN 512
#define ALPHA 0.1f
#define EPS_BN 1e-5f
#define M_TILE 128
#define BK 64

// ---- CSR build: 256-node bins, tile-staged counting sort ----
#define CBITS 8
#define CNODES 256
#define NCBIN 391            // ceil(100000/256)
#define TILE 8192
#define EPT 32               // edges per thread (256 threads * 32 = 8192)
#define BINCAP 9216          // per-bin fixed capacity (mean 8192 + 11 sigma)

// ---- propagation: 4 threads/node, LDS-staged indices, 8B packed zt ----
#define NPB 64               // nodes per block (4 threads/node, 256 threads)
#define NB2 1563             // ceil(100000/64)
#define LCAP3 3072           // index slice capacity (mean 2048 + ~22 sigma)

typedef float f32x4 __attribute__((ext_vector_type(4)));
typedef __bf16 bf16x8 __attribute__((ext_vector_type(8)));
typedef unsigned short u16x8 __attribute__((ext_vector_type(8)));
typedef unsigned short u16x4 __attribute__((ext_vector_type(4)));
typedef unsigned long long u64;

__device__ __forceinline__ unsigned short f2bf(float f) {
  unsigned u = __float_as_uint(f);
  u += 0x7fffu + ((u >> 16) & 1u);   // RNE
  return (unsigned short)(u >> 16);
}
__device__ __forceinline__ float bf2f(unsigned short h) {
  return __uint_as_float(((unsigned)h) << 16);
}
// HW packed f32->bf16 (RNE): 1 VALU op per 2 elements (vs ~7 for 2x manual f2bf).
__device__ __forceinline__ unsigned cvt_pk_bf16(float lo, float hi) {
  unsigned r;
  asm volatile("v_cvt_pk_bf16_f32 %0, %1, %2" : "=v"(r) : "v"(lo), "v"(hi));
  return r;
}

// zt packed as 3xf16 in 8B (dwordx2 gathers).
__device__ __forceinline__ u64 pk3(float x, float y, float z) {
  unsigned short a = __builtin_bit_cast(unsigned short, (_Float16)x);  // RNE
  unsigned short b = __builtin_bit_cast(unsigned short, (_Float16)y);
  unsigned short c = __builtin_bit_cast(unsigned short, (_Float16)z);
  return (u64)a | ((u64)b << 16) | ((u64)c << 32);
}
__device__ __forceinline__ void up3(u64 p, float& sx, float& sy, float& sz) {
  unsigned lo = (unsigned)p, hi = (unsigned)(p >> 32);
  sx += (float)__builtin_bit_cast(_Float16, (unsigned short)(lo & 0xFFFFu));
  sy += (float)__builtin_bit_cast(_Float16, (unsigned short)(lo >> 16));
  sz += (float)__builtin_bit_cast(_Float16, (unsigned short)(hi & 0xFFFFu));
}

// ---------------- prep: fold BN into weights (bf16) + biases, zero bin cursors ----------------
__global__ void k_prep(const float* __restrict__ w1, const float* __restrict__ b1,
                       const float* __restrict__ g1, const float* __restrict__ be1,
                       const float* __restrict__ m1, const float* __restrict__ v1,
                       const float* __restrict__ w2, const float* __restrict__ b2,
                       const float* __restrict__ g2, const float* __restrict__ be2,
                       const float* __restrict__ m2, const float* __restrict__ v2,
                       unsigned short* __restrict__ w1b, unsigned short* __restrict__ w2b,
                       float* __restrict__ bias1, float* __restrict__ bias2,
                       int* __restrict__ bincur) {
  int idx = blockIdx.x * 256 + threadIdx.x;
  if (idx < 65536) {                       // w1: [128][512], scale row n by s1[n]
    int n = idx >> 9;
    float s = g1[n] * rsqrtf(v1[n] + EPS_BN);
    w1b[idx] = f2bf(w1[idx] * s);
  } else if (idx < 81920) {                // w2: [128][128]
    int i = idx - 65536;
    int n = i >> 7;
    float s = g2[n] * rsqrtf(v2[n] + EPS_BN);
    w2b[i] = f2bf(w2[i] * s);
  } else if (idx < 82048) {
    int c = idx - 81920;
    float s = g1[c] * rsqrtf(v1[c] + EPS_BN);
    bias1[c] = (b1[c] - m1[c]) * s + be1[c];
  } else if (idx < 82176) {
    int c = idx - 82048;
    float s = g2[c] * rsqrtf(v2[c] + EPS_BN);
    bias2[c] = (b2[c] - m2[c]) * s + be2[c];
  }
  int bi = idx - 82176;
  if (bi >= 0 && bi < NCBIN) bincur[bi] = 0;
}

// ---------------- pass A: tile-staged bin scatter into fixed-capacity bin regions ----------------
// sbin[] records each staged edge's bin at scatter time -> copy-out is a direct
// lookup instead of a 9-step binary search per edge.
__global__ __launch_bounds__(256) void k_binA(const int* __restrict__ src,
                                              const int* __restrict__ dst, int E,
                                              int* __restrict__ bincur,
                                              unsigned* __restrict__ binned) {
  __shared__ unsigned stage[TILE];
  __shared__ unsigned short sbin[TILE];
  __shared__ int cnt[NCBIN];
  __shared__ int loff[NCBIN + 1];
  __shared__ int goff[NCBIN];
  __shared__ int sc[2][256];
  const int tid = threadIdx.x;

  for (int i = tid; i < NCBIN; i += 256) cnt[i] = 0;
  __syncthreads();

  const int e0 = blockIdx.x * TILE;
  const int n = min(TILE, E - e0);

  unsigned pk[EPT];
  int bp[EPT];
#pragma unroll
  for (int i = 0; i < EPT; ++i) {
    int o = i * 256 + tid;
    if (o < n) {
      int e = e0 + o;
      int d = dst[e];
      int s = src[e];
      int b = d >> CBITS;
      pk[i] = (unsigned)s | ((unsigned)(d & (CNODES - 1)) << 17);
      int p = atomicAdd(&cnt[b], 1);
      bp[i] = b | (p << 9);             // b: 9 bits, p: <= 13 bits
    } else bp[i] = -1;
  }
  __syncthreads();

  // exclusive scan of cnt[391] (pairs -> Hillis-Steele over 256)
  int c0 = (2 * tid     < NCBIN) ? cnt[2 * tid]     : 0;
  int c1 = (2 * tid + 1 < NCBIN) ? cnt[2 * tid + 1] : 0;
  sc[0][tid] = c0 + c1;
  __syncthreads();
  int cur = 0;
#pragma unroll
  for (int off = 1; off < 256; off <<= 1) {
    sc[cur ^ 1][tid] = sc[cur][tid] + ((tid >= off) ? sc[cur][tid - off] : 0);
    __syncthreads();
    cur ^= 1;
  }
  int ex = sc[cur][tid] - (c0 + c1);
  if (2 * tid < NCBIN) loff[2 * tid] = ex;
  if (2 * tid + 1 < NCBIN) loff[2 * tid + 1] = ex + c0;
  if (tid == 255) loff[NCBIN] = sc[cur][255];
  __syncthreads();
  // reserve global space per bin
  for (int i = tid; i < NCBIN; i += 256)
    if (cnt[i] > 0) goff[i] = atomicAdd(&bincur[i], cnt[i]);
  __syncthreads();

  // scatter into LDS stage (bin-sorted within tile), record bin id
#pragma unroll
  for (int i = 0; i < EPT; ++i) {
    if (bp[i] >= 0) {
      int b = bp[i] & 511;
      int p = bp[i] >> 9;
      int addr = loff[b] + p;
      stage[addr] = pk[i];
      sbin[addr] = (unsigned short)b;
    }
  }
  __syncthreads();

  // linear copy-out: contiguous runs per bin, direct bin lookup
  for (int i = tid; i < n; i += 256) {
    int b = sbin[i];
    binned[(size_t)b * BINCAP + goff[b] + (i - loff[b])] = stage[i];
  }
}

// ---------------- fused pass B: count + scan + row_start/dinv + sort (one kernel) ----------------
__global__ __launch_bounds__(256) void k_binB(const unsigned* __restrict__ binned,
                                              const int* __restrict__ bincur,
                                              int* __restrict__ row_start,
                                              float* __restrict__ dinv,
                                              unsigned* __restrict__ csr_col, int E) {
  __shared__ unsigned ebuf[BINCAP];
  __shared__ unsigned sortbuf[BINCAP];
  __shared__ int lcnt[CNODES];
  __shared__ int lcur[CNODES];
  __shared__ int sb[2][256];
  __shared__ int red[4];
  const int b = blockIdx.x;
  const int t = threadIdx.x;

  // rs0 = sum of bincur[0..b)
  int part = 0;
  for (int i = t; i < b; i += 256) part += bincur[i];
#pragma unroll
  for (int off = 32; off > 0; off >>= 1) part += __shfl_down(part, off, 64);
  if ((t & 63) == 0) red[t >> 6] = part;
  lcnt[t] = 0;
  __syncthreads();
  const int rs0 = (red[0] + red[1]) + (red[2] + red[3]);
  int cnt = bincur[b];
  if (cnt > BINCAP) cnt = BINCAP;

  // read binned slice once into LDS + count degrees
  const unsigned* bp = binned + (size_t)b * BINCAP;
  for (int i = t; i < cnt; i += 256) {
    unsigned v = bp[i];
    ebuf[i] = v;
    atomicAdd(&lcnt[v >> 17], 1);
  }
  __syncthreads();

  // exclusive scan of lcnt[256]
  sb[0][t] = lcnt[t];
  __syncthreads();
  int cur = 0;
#pragma unroll
  for (int off = 1; off < 256; off <<= 1) {
    sb[cur ^ 1][t] = sb[cur][t] + ((t >= off) ? sb[cur][t - off] : 0);
    __syncthreads();
    cur ^= 1;
  }
  int ex = sb[cur][t] - lcnt[t];

  const int node0 = b << CBITS;
  const int node = node0 + t;
  if (node < N_NODES) {
    row_start[node] = rs0 + ex;
    dinv[node] = rsqrtf((float)(lcnt[t] + 1));   // +1 self-loop
  }
  if (node == N_NODES) row_start[N_NODES] = E;
  if (b == NCBIN - 1 && t == 255) row_start[N_NODES] = E;
  lcur[t] = ex;
  __syncthreads();

  // LDS-cursor sort -> coalesced csr_col write
  for (int i = t; i < cnt; i += 256) {
    unsigned v = ebuf[i];
    int p = atomicAdd(&lcur[v >> 17], 1);
    sortbuf[p] = v & 0x1FFFFu;
  }
  __syncthreads();
  for (int i = t; i < cnt; i += 256) csr_col[rs0 + i] = sortbuf[i];
}

// ---------------- fused MLP: x -> h0[N,4], zt0 = pk3(dinv*h0) ----------------
__global__ __launch_bounds__(256, 2) void k_mlp(
    const float* __restrict__ x, const unsigned short* __restrict__ w1b,
    const unsigned short* __restrict__ w2b, const float* __restrict__ bias1,
    const float* __restrict__ bias2, const float* __restrict__ w3,
    const float* __restrict__ b3, const float* __restrict__ dinv,
    float4* __restrict__ h0, u64* __restrict__ zt) {
  __shared__ unsigned short arena[35840];
  __shared__ float lds_w3[384];
  unsigned short* lds_x = arena;
  unsigned short* lds_w = arena + 9216;
  unsigned short* lds_h = arena;
  unsigned short* lds_w2 = arena + 18432;

  const int tid = threadIdx.x;
  const int lane = tid & 63;
  const int wv = tid >> 6;
  const int fr = lane & 15;
  const int kq = (lane >> 4) * 8;
  const int rq = (lane >> 4) * 4;
  const int row0 = blockIdx.x * M_TILE;

  for (int i = tid; i < 384; i += 256) lds_w3[i] = w3[i];

#pragma unroll
  for (int it = 0; it < 8; ++it) {
    int idx = it * 256 + tid;
    int n = idx >> 4, c8 = idx & 15;
    uint4 v = *(const uint4*)(w2b + n * 128 + c8 * 8);
    *(uint4*)(lds_w2 + n * 136 + c8 * 8) = v;
  }

  f32x4 xr[8];
#pragma unroll
  for (int it = 0; it < 8; ++it) {
    int idx = it * 256 + tid;
    int r = idx >> 4, c4 = idx & 15;
    int gm = row0 + r;
    if (gm >= N_NODES) gm = N_NODES - 1;
    xr[it] = *(const f32x4*)(x + (size_t)gm * D_IN + 0 + c4 * 4);
  }

  f32x4 zero4 = {0.f, 0.f, 0.f, 0.f};
  f32x4 acc[2][8];
#pragma unroll
  for (int mt = 0; mt < 2; ++mt)
#pragma unroll
    for (int nt = 0; nt < 8; ++nt) acc[mt][nt] = zero4;

  for (int kb = 0; kb < D_IN; kb += BK) {
    // publish prefetched x tile via HW packed cvt (2 ops per 4 elems vs ~14)
#pragma unroll
    for (int it = 0; it < 8; ++it) {
      int idx = it * 256 + tid;
      int r = idx >> 4, c4 = idx & 15;
      uint2 o;
      o.x = cvt_pk_bf16(xr[it].x, xr[it].y);
      o.y = cvt_pk_bf16(xr[it].z, xr[it].w);
      *(uint2*)(lds_x + r * 72 + c4 * 4) = o;
    }
#pragma unroll
    for (int it = 0; it < 4; ++it) {
      int idx = it * 256 + tid;
      int n = idx >> 3, c8 = idx & 7;
      uint4 v = *(const uint4*)(w1b + n * 512 + kb + c8 * 8);
      *(uint4*)(lds_w + n * 72 + c8 * 8) = v;
    }
    __syncthreads();
    if (kb + BK < D_IN) {
#pragma unroll
      for (int it = 0; it < 8; ++it) {
        int idx = it * 256 + tid;
        int r = idx >> 4, c4 = idx & 15;
        int gm = row0 + r;
        if (gm >= N_NODES) gm = N_NODES - 1;
        xr[it] = *(const f32x4*)(x + (size_t)gm * D_IN + (kb + BK) + c4 * 4);
      }
    }
#pragma unroll
    for (int kk = 0; kk < BK; kk += 32) {
      bf16x8 a[2], b[8];
#pragma unroll
      for (int mt = 0; mt < 2; ++mt)
        a[mt] = __builtin_bit_cast(bf16x8, *(const u16x8*)(lds_x + (wv * 32 + mt * 16 + fr) * 72 + kk + kq));
#pragma unroll
      for (int nt = 0; nt < 8; ++nt)
        b[nt] = __builtin_bit_cast(bf16x8, *(const u16x8*)(lds_w + (nt * 16 + fr) * 72 + kk + kq));
#pragma unroll
      for (int mt = 0; mt < 2; ++mt)
#pragma unroll
        for (int nt = 0; nt < 8; ++nt)
          acc[mt][nt] = __builtin_amdgcn_mfma_f32_16x16x32_bf16(a[mt], b[nt], acc[mt][nt], 0, 0, 0);
    }
    __syncthreads();
  }

  float b1v[8], b2v[8];
#pragma unroll
  for (int nt = 0; nt < 8; ++nt) {
    b1v[nt] = bias1[nt * 16 + fr];
    b2v[nt] = bias2[nt * 16 + fr];
  }
  float hr[2][8][4];
#pragma unroll
  for (int mt = 0; mt < 2; ++mt)
#pragma unroll
    for (int nt = 0; nt < 8; ++nt)
#pragma unroll
      for (int r = 0; r < 4; ++r) {
        int rl = wv * 32 + mt * 16 + rq + r;
        int cl = nt * 16 + fr;
        float h = acc[mt][nt][r] + b1v[nt];
        h = h > 0.f ? h : 0.f;
        hr[mt][nt][r] = h;
        lds_h[rl * 136 + cl] = f2bf(h);
      }
  __syncthreads();

  f32x4 acc2[2][8];
#pragma unroll
  for (int mt = 0; mt < 2; ++mt)
#pragma unroll
    for (int nt = 0; nt < 8; ++nt) acc2[mt][nt] = zero4;
#pragma unroll
  for (int kk = 0; kk < 128; kk += 32) {
    bf16x8 a[2], b[8];
#pragma unroll
    for (int mt = 0; mt < 2; ++mt)
      a[mt] = __builtin_bit_cast(bf16x8, *(const u16x8*)(lds_h + (wv * 32 + mt * 16 + fr) * 136 + kk + kq));
#pragma unroll
    for (int nt = 0; nt < 8; ++nt)
      b[nt] = __builtin_bit_cast(bf16x8, *(const u16x8*)(lds_w2 + (nt * 16 + fr) * 136 + kk + kq));
#pragma unroll
    for (int mt = 0; mt < 2; ++mt)
#pragma unroll
      for (int nt = 0; nt < 8; ++nt)
        acc2[mt][nt] = __builtin_amdgcn_mfma_f32_16x16x32_bf16(a[mt], b[nt], acc2[mt][nt], 0, 0, 0);
  }
  __syncthreads();

#pragma unroll
  for (int mt = 0; mt < 2; ++mt)
#pragma unroll
    for (int nt = 0; nt < 8; ++nt)
#pragma unroll
      for (int r = 0; r < 4; ++r) {
        int rl = wv * 32 + mt * 16 + rq + r;
        int cl = nt * 16 + fr;
        float t2 = acc2[mt][nt][r] + b2v[nt];
        t2 = t2 > 0.f ? t2 : 0.f;
        lds_h[rl * 136 + cl] = f2bf(hr[mt][nt][r] + t2);
      }
  __syncthreads();

  if (tid < 128) {
    int m = tid;
    int gm = row0 + m;
    if (gm < N_NODES) {
      float a0 = 0.f, a1 = 0.f, a2 = 0.f;
#pragma unroll 8
      for (int c = 0; c < 128; ++c) {
        float hv = bf2f(lds_h[m * 136 + c]);
        a0 += hv * lds_w3[c];
        a1 += hv * lds_w3[128 + c];
        a2 += hv * lds_w3[256 + c];
      }
      float z0 = a0 + b3[0], z1 = a1 + b3[1], z2 = a2 + b3[2];
      float di = dinv[gm];
      h0[gm] = make_float4(z0, z1, z2, 0.f);
      zt[gm] = pk3(di * z0, di * z1, di * z2);
    }
  }
}

// ---------------- one APPNP iteration (4 threads/node, LDS idx, 8B packed gathers) ----------------
#define GATHER_BODY(IDX)                                                        \
  for (; j + 8 <= je; j += 8) {                                                 \
    u64 p0 = zin[IDX(j + 0)], p1 = zin[IDX(j + 1)];                             \
    u64 p2 = zin[IDX(j + 2)], p3 = zin[IDX(j + 3)];                             \
    u64 p4 = zin[IDX(j + 4)], p5 = zin[IDX(j + 5)];                             \
    u64 p6 = zin[IDX(j + 6)], p7 = zin[IDX(j + 7)];                             \
    up3(p0, sx, sy, sz); up3(p1, sx, sy, sz);                                   \
    up3(p2, sx, sy, sz); up3(p3, sx, sy, sz);                                   \
    up3(p4, sx, sy, sz); up3(p5, sx, sy, sz);                                   \
    up3(p6, sx, sy, sz); up3(p7, sx, sy, sz);                                   \
  }                                                                             \
  if (j + 4 <= je) {                                                            \
    u64 p0 = zin[IDX(j + 0)], p1 = zin[IDX(j + 1)];                             \
    u64 p2 = zin[IDX(j + 2)], p3 = zin[IDX(j + 3)];                             \
    up3(p0, sx, sy, sz); up3(p1, sx, sy, sz);                                   \
    up3(p2, sx, sy, sz); up3(p3, sx, sy, sz);                                   \
    j += 4;                                                                     \
  }                                                                             \
  if (j + 2 <= je) {                                                            \
    u64 p0 = zin[IDX(j + 0)], p1 = zin[IDX(j + 1)];                             \
    up3(p0, sx, sy, sz); up3(p1, sx, sy, sz);                                   \
    j += 2;                                                                     \
  }                                                                             \
  if (j < je) { u64 p0 = zin[IDX(j)]; up3(p0, sx, sy, sz); }

template <bool FINAL>
__global__ __launch_bounds__(256) void k_iter2(
    const u64* __restrict__ zin, u64* __restrict__ zout,
    const int* __restrict__ row_start, const unsigned* __restrict__ csr_col,
    const float* __restrict__ dinv, const float4* __restrict__ h0v,
    float* __restrict__ out) {
  __shared__ unsigned lidx[LCAP3];
  __shared__ float psum[3][NPB][3];
  __shared__ int srs[2];
  const int t = threadIdx.x;
  const int q = t >> 6;             // wave index = quarter of the row
  const int tn = t & 63;
  const int node0 = blockIdx.x * NPB;
  const int node = node0 + tn;
  const bool valid = node < N_NODES;

  if (t == 0) srs[0] = row_start[node0];
  if (t == 1) srs[1] = row_start[min(node0 + NPB, N_NODES)];
  __syncthreads();
  const int rs0 = srs[0];
  const int cnt = srs[1] - rs0;
  const bool use_lds = (cnt <= LCAP3);
  if (use_lds) {
    for (int i = t; i < cnt; i += 256) lidx[i] = csr_col[rs0 + i];
  }

  int jb = 0, je = 0;
  if (valid) {
    int r0 = row_start[node];
    int r1 = row_start[node + 1];
    int len = r1 - r0;
    jb = r0 + ((len * q) >> 2);
    je = r0 + ((len * (q + 1)) >> 2);
  }
  __syncthreads();

  float sx = 0.f, sy = 0.f, sz = 0.f;
  if (use_lds) {
    int j = jb - rs0;
    je -= rs0;
#define IDXL(J) lidx[J]
    GATHER_BODY(IDXL)
#undef IDXL
  } else {
    int j = jb;
#define IDXG(J) csr_col[J]
    GATHER_BODY(IDXG)
#undef IDXG
  }

  if (q) { psum[q - 1][tn][0] = sx; psum[q - 1][tn][1] = sy; psum[q - 1][tn][2] = sz; }
  __syncthreads();
  if (q == 0 && valid) {
    up3(zin[node], sx, sy, sz);       // self-loop term
    float4 h = h0v[node];
    float di = dinv[node];
    sx += (psum[0][tn][0] + psum[1][tn][0]) + psum[2][tn][0];
    sy += (psum[0][tn][1] + psum[1][tn][1]) + psum[2][tn][1];
    sz += (psum[0][tn][2] + psum[1][tn][2]) + psum[2][tn][2];
    float zx = (1.f - ALPHA) * di * sx + ALPHA * h.x;
    float zy = (1.f - ALPHA) * di * sy + ALPHA * h.y;
    float zz = (1.f - ALPHA) * di * sz + ALPHA * h.z;
    if (!FINAL) {
      zout[node] = pk3(di * zx, di * zy, di * zz);
    } else {
      float mx = fmaxf(zx, fmaxf(zy, zz));
      float l = logf(expf(zx - mx) + expf(zy - mx) + expf(zz - mx));
      out[node * 3 + 0] = zx - mx - l;
      out[node * 3 + 1] = zy - mx - l;
      out[node * 3 + 2] = zz - mx - l;
    }
  }
}

extern "C" void kernel_launch(void* const* d_in, const int* in_sizes, int n_in,
                              void* d_out, int out_size, void* d_ws, size_t ws_size,
                              hipStream_t stream) {
  const float* x   = (const float*)d_in[0];
  const int*   ei  = (const int*)d_in[1];
  const float* w1  = (const float*)d_in[2];
  const float* b1  = (const float*)d_in[3];
  const float* g1  = (const float*)d_in[4];
  const float* be1 = (const float*)d_in[5];
  const float* m1  = (const float*)d_in[6];
  const float* v1  = (const float*)d_in[7];
  const float* w2  = (const float*)d_in[8];
  const float* b2  = (const float*)d_in[9];
  const float* g2  = (const float*)d_in[10];
  const float* be2 = (const float*)d_in[11];
  const float* m2  = (const float*)d_in[12];
  const float* v2  = (const float*)d_in[13];
  const float* w3  = (const float*)d_in[14];
  const float* b3  = (const float*)d_in[15];

  const int E = in_sizes[1] / 2;
  const int* srcA = ei;
  const int* dstA = ei + E;

  char* w = (char*)d_ws;
  size_t off = 0;
  auto alloc = [&](size_t bytes) -> void* {
    void* p = w + off;
    off = (off + bytes + 255) & ~(size_t)255;
    return p;
  };
  unsigned short* w1b   = (unsigned short*)alloc(65536 * 2);
  unsigned short* w2b   = (unsigned short*)alloc(16384 * 2);
  float* bias1          = (float*)alloc(128 * 4);
  float* bias2          = (float*)alloc(128 * 4);
  int*   row_start      = (int*)alloc(((size_t)N_NODES + 1) * 4);
  float* dinv           = (float*)alloc((size_t)N_NODES * 4);
  int*   bincur         = (int*)alloc((size_t)NCBIN * 4);
  float4* h0            = (float4*)alloc((size_t)N_NODES * 16);
  u64*   ztA            = (u64*)alloc((size_t)N_NODES * 8);
  u64*   ztB            = (u64*)alloc((size_t)N_NODES * 8);
  unsigned* csr_col     = (unsigned*)alloc((size_t)E * 4);
  unsigned* binned      = (unsigned*)alloc((size_t)NCBIN * BINCAP * 4);

  const int NTILE = (E + TILE - 1) / TILE;     // 391 for E=3.2M

  k_prep<<<(82176 + NCBIN + 255) / 256, 256, 0, stream>>>(
      w1, b1, g1, be1, m1, v1, w2, b2, g2, be2, m2, v2, w1b, w2b, bias1, bias2, bincur);
  k_binA<<<NTILE, 256, 0, stream>>>(srcA, dstA, E, bincur, binned);
  k_binB<<<NCBIN, 256, 0, stream>>>(binned, bincur, row_start, dinv, csr_col, E);
  k_mlp<<<(N_NODES + M_TILE - 1) / M_TILE, 256, 0, stream>>>(
      x, w1b, w2b, bias1, bias2, w3, b3, dinv, h0, ztA);

  const u64* zin = ztA;
  u64* zout = ztB;
  for (int k = 0; k < 9; ++k) {
    k_iter2<false><<<NB2, 256, 0, stream>>>(zin, zout, row_start, csr_col, dinv, h0, nullptr);
    const u64* tswap = zout;
    zout = (u64*)zin;
    zin = tswap;
  }
  k_iter2<true><<<NB2, 256, 0, stream>>>(zin, nullptr, row_start, csr_col, dinv, h0, (float*)d_out);
}